// Round 6
// baseline (7654.228 us; speedup 1.0000x reference)
//
#include <hip/hip_runtime.h>
#include <cstdint>

// CORRECTNESS ANCHOR: all-naive fp32 pipeline, fp32 outputs.
// Problem: B=4, N=1024, C=768, H=12, hd=64
// Inputs fp32: x[4,1024,768], qkv_w[2304,768], qkv_b[2304], proj_w[768,768],
//              proj_b[768], cls_bias[12]
// Outputs fp32 concat: out[4,1024,768] then attn[4,12,1024,1024]
#define OUT0_ELEMS 3145728   // 4096*768
#define QKV_F32    3145728   // 48*1024*64 elements per tensor

// ---------------------------------------------------------------------------
// qkv = x @ qkv_w.T + qkv_b, scattered to Q(*0.125)/K/V, all fp32.
// Layout: Q,K,V [bh][n][d]. One thread per (m, o). block: 16 o x 16 m.
// ---------------------------------------------------------------------------
__global__ __launch_bounds__(256)
void qkv_naive(const float* __restrict__ x, const float* __restrict__ w,
               const float* __restrict__ bias,
               float* __restrict__ Q, float* __restrict__ K, float* __restrict__ V)
{
    const int o = blockIdx.x * 16 + (threadIdx.x & 15);   // [0,2304)
    const int m = blockIdx.y * 16 + (threadIdx.x >> 4);   // [0,4096)
    const float* xr = x + (size_t)m * 768;
    const float* wr = w + (size_t)o * 768;
    float acc = bias[o];
    for (int k = 0; k < 768; ++k) acc = fmaf(xr[k], wr[k], acc);
    const int sidx = o / 768, rem = o % 768;
    const int h = rem >> 6, d = rem & 63;
    const int b = m >> 10, n = m & 1023;
    const size_t idx = (((size_t)(b * 12 + h)) * 1024 + n) * 64 + d;
    if (sidx == 0)      Q[idx] = acc * 0.125f;
    else if (sidx == 1) K[idx] = acc;
    else                V[idx] = acc;
}

// ---------------------------------------------------------------------------
// scores + softmax + row0 fix, fp32; writes attn fp32 to d_out region.
// block = (bh, 8 queries); serial per-query softmax mirroring numpy exactly.
// ---------------------------------------------------------------------------
__global__ __launch_bounds__(256)
void scores_naive(const float* __restrict__ Q, const float* __restrict__ K,
                  const float* __restrict__ cls_bias, float* __restrict__ attn)
{
    __shared__ float s[8 * 1024];   // 32 KB
    const int tid = threadIdx.x;
    const int bh = blockIdx.y, rt = blockIdx.x;   // rt in [0,128)
    const int qi = tid >> 5, sub = tid & 31;
    const int qglob = rt * 8 + qi;
    const float* Qrow = Q + ((size_t)bh * 1024 + qglob) * 64;
    const float* Kb = K + (size_t)bh * 1024 * 64;

    for (int key = sub; key < 1024; key += 32) {
        const float* Kr = Kb + (size_t)key * 64;
        float a = 0.f;
        for (int d = 0; d < 64; ++d) a = fmaf(Qrow[d], Kr[d], a);
        s[qi * 1024 + key] = a;
    }
    __syncthreads();

    if (tid < 8) {
        float* row = s + tid * 1024;
        float mx = -3.0e38f;
        for (int k = 0; k < 1024; ++k) mx = fmaxf(mx, row[k]);
        float sm = 0.f;
        for (int k = 0; k < 1024; ++k) { float e = expf(row[k] - mx); row[k] = e; sm += e; }
        float inv = 1.0f / sm;
        for (int k = 0; k < 1024; ++k) row[k] *= inv;
        if (rt == 0 && tid == 0) {   // global query 0 of this (b,h)
            float p0 = row[0];
            float a00 = fminf(fmaxf(p0 + cls_bias[bh % 12], 0.f), 1.f);
            float actual = 0.f;
            for (int k = 1; k < 1024; ++k) actual += row[k];
            float mp = (1.0f - a00) / (actual + 1e-6f);
            row[0] = a00;
            for (int k = 1; k < 1024; ++k)
                row[k] = fminf(fmaxf(row[k] * mp, 0.f), 1.f);
        }
    }
    __syncthreads();

    float* arow = attn + (size_t)bh * 1024 * 1024 + (size_t)qglob * 1024;
    for (int key = sub; key < 1024; key += 32)
        arow[key] = s[qi * 1024 + key];
}

// ---------------------------------------------------------------------------
// O1[b][m][h*64+d] = sum_k attn[bh][m][k] * V[bh][k][d]   (fp32)
// wave: same m for 64 lanes (attn broadcast), d = lane (V coalesced).
// ---------------------------------------------------------------------------
__global__ __launch_bounds__(256)
void attnv_naive(const float* __restrict__ attn, const float* __restrict__ V,
                 float* __restrict__ O1)
{
    const int tid = threadIdx.x;
    const int bh = blockIdx.y;
    const int m = blockIdx.x * 4 + (tid >> 6);
    const int d = tid & 63;
    const float* Pr = attn + (size_t)bh * 1024 * 1024 + (size_t)m * 1024;
    const float* Vb = V + (size_t)bh * 1024 * 64 + d;
    float acc = 0.f;
    for (int k = 0; k < 1024; ++k) acc = fmaf(Pr[k], Vb[(size_t)k * 64], acc);
    const int b = bh / 12, h = bh % 12;
    O1[((size_t)b * 1024 + m) * 768 + (size_t)h * 64 + d] = acc;
}

// ---------------------------------------------------------------------------
// out = O1 @ proj_w.T + proj_b  (fp32 in/out). One thread per (m,o).
// ---------------------------------------------------------------------------
__global__ __launch_bounds__(256)
void proj_naive(const float* __restrict__ O1, const float* __restrict__ w,
                const float* __restrict__ bias, float* __restrict__ out)
{
    const int o = blockIdx.x * 16 + (threadIdx.x & 15);   // [0,768)
    const int m = blockIdx.y * 16 + (threadIdx.x >> 4);   // [0,4096)
    const float* ar = O1 + (size_t)m * 768;
    const float* wr = w + (size_t)o * 768;
    float acc = bias[o];
    for (int k = 0; k < 768; ++k) acc = fmaf(ar[k], wr[k], acc);
    out[(size_t)m * 768 + o] = acc;
}

extern "C" void kernel_launch(void* const* d_in, const int* in_sizes, int n_in,
                              void* d_out, int out_size, void* d_ws, size_t ws_size,
                              hipStream_t stream) {
    const float* x        = (const float*)d_in[0];
    const float* qkv_w    = (const float*)d_in[1];
    const float* qkv_b    = (const float*)d_in[2];
    const float* proj_w   = (const float*)d_in[3];
    const float* proj_b   = (const float*)d_in[4];
    const float* cls_bias = (const float*)d_in[5];

    float* out  = (float*)d_out;
    float* attn = out + OUT0_ELEMS;   // fp32 outputs, concatenated

    float* ws = (float*)d_ws;
    float* Q  = ws;                         // 12.6 MB
    float* K  = Q  + (size_t)QKV_F32;       // 12.6 MB
    float* V  = K  + (size_t)QKV_F32;       // 12.6 MB
    float* O1 = V  + (size_t)QKV_F32;       // 12.6 MB  (total ~50 MB)

    // 1) qkv = x @ qkv_w.T + qkv_b -> Q(scaled)/K/V, fp32
    qkv_naive<<<dim3(144, 256), 256, 0, stream>>>(x, qkv_w, qkv_b, Q, K, V);
    // 2) attn = row0-fixed softmax(Q K^T), fp32 (output 1)
    scores_naive<<<dim3(128, 48), 256, 0, stream>>>(Q, K, cls_bias, attn);
    // 3) O1 = attn @ V, fp32
    attnv_naive<<<dim3(256, 48), 256, 0, stream>>>(attn, V, O1);
    // 4) out = O1 @ proj_w.T + proj_b, fp32 (output 0)
    proj_naive<<<dim3(48, 256), 256, 0, stream>>>(O1, proj_w, proj_b, out);
}